// Round 10
// baseline (999.944 us; speedup 1.0000x reference)
//
#include <hip/hip_runtime.h>
#include <stdint.h>

typedef __attribute__((ext_vector_type(8))) short short8;    // MFMA A/B frag (8 bf16)
typedef __attribute__((ext_vector_type(4))) float floatx4;   // MFMA C/D frag

// ---------- bf16 helpers ----------
static __device__ __forceinline__ float b2f(uint16_t b){
    return __uint_as_float(((uint32_t)b) << 16);
}
static __device__ __forceinline__ uint16_t f2b(float f){
    uint32_t u = __float_as_uint(f);
    return (uint16_t)((u + 0x7fffu + ((u >> 16) & 1u)) >> 16);
}
static __device__ __forceinline__ float blo(uint32_t v){ return __uint_as_float(v << 16); }
static __device__ __forceinline__ float bhi(uint32_t v){ return __uint_as_float(v & 0xffff0000u); }
static __device__ __forceinline__ uint32_t pack2(float a, float b){
    return ((uint32_t)f2b(b) << 16) | (uint32_t)f2b(a);
}

// ---------- sentinel (only used when ws too small) ----------
__global__ void k_sentinel(uint32_t* out, int nwords, uint32_t pat){
    int i = blockIdx.x * blockDim.x + threadIdx.x;
    if (i < nwords) out[i] = pat;
}

// ---------- dtype flags: flags[0]=edge_is_int64, flags[1]=x_is_bf16 ----------
__global__ void k_flags(const uint32_t* xw, const int* ei, int* flags){
    if (threadIdx.x != 0 || blockIdx.x != 0) return;
    int odd_nz = 0;
    for (int k = 0; k < 128; k++){
        if (ei[2 * k + 1] != 0) odd_nz = 1;
    }
    flags[0] = odd_nz ? 0 : 1;
    int big = 0;
    for (int k = 0; k < 128; k++){
        float lo = __uint_as_float(xw[k] << 16);
        if (!(fabsf(lo) <= 1024.0f)) big = 1;
    }
    flags[1] = big ? 0 : 1;
}

// ---------- zero deg[N] ----------
__global__ void k_zero(int* deg, int N){
    int i = blockIdx.x * blockDim.x + threadIdx.x;
    if (i < N) deg[i] = 0;
}

// ---------- CSR build ----------
__global__ void k_deg(const int* ei, int E, int* deg, const int* flags){
    int e = blockIdx.x * blockDim.x + threadIdx.x;
    if (e < E){
        int d = flags[0] ? ei[2 * e] : ei[e];
        atomicAdd(&deg[d], 1);
    }
}

__global__ void k_scan1(const int* deg, int N, int* bsum){
    __shared__ int s[256];
    int t = threadIdx.x;
    int i = blockIdx.x * 256 + t;
    s[t] = (i < N) ? deg[i] : 0;
    __syncthreads();
    for (int off = 128; off > 0; off >>= 1){
        if (t < off) s[t] += s[t + off];
        __syncthreads();
    }
    if (t == 0) bsum[blockIdx.x] = s[0];
}

__global__ void k_scan2(int* bsum, int nb, int* rp, int N){
    __shared__ int s[512];
    int t = threadIdx.x;
    int v = (t < nb) ? bsum[t] : 0;
    s[t] = v;
    __syncthreads();
    for (int off = 1; off < 512; off <<= 1){
        int u = (t >= off) ? s[t - off] : 0;
        __syncthreads();
        s[t] += u;
        __syncthreads();
    }
    if (t < nb) bsum[t] = s[t] - v;
    if (t == 511) rp[N] = s[511];
}

__global__ void k_scan3(const int* deg, int N, const int* bpre, int* rp, int* cur){
    __shared__ int s[256];
    int t = threadIdx.x;
    int i = blockIdx.x * 256 + t;
    int v = (i < N) ? deg[i] : 0;
    s[t] = v;
    __syncthreads();
    for (int off = 1; off < 256; off <<= 1){
        int u = (t >= off) ? s[t - off] : 0;
        __syncthreads();
        s[t] += u;
        __syncthreads();
    }
    if (i < N){
        int ex = bpre[blockIdx.x] + s[t] - v;
        rp[i] = ex;
        cur[i] = ex;
    }
}

__global__ void k_fill(const int* ei, int E, int* cur, int* col, const int* flags){
    int e = blockIdx.x * blockDim.x + threadIdx.x;
    if (e < E){
        int is64 = flags[0];
        int d = is64 ? ei[2 * e] : ei[e];
        int sv = is64 ? ei[2 * (E + e)] : ei[E + e];
        int p = atomicAdd(&cur[d], 1);
        col[p] = sv;
    }
}

// ---------- input conversion (early-out when x already bf16) ----------
__global__ void k_cvt_x(const void* x, uint16_t* hx, int n, const int* flags){
    if (flags[1]) return;   // layer-0 k_agg reads raw x directly in bf16 case
    int i = blockIdx.x * blockDim.x + threadIdx.x;
    if (i >= n) return;
    hx[i] = f2b(((const float*)x)[i]);
}

// ---------- all W fragment reorders in ONE launch ----------
__global__ void k_prep_all(const void* W0, const void* W1, const void* W2, const void* Wl,
                           uint16_t* Wf0, uint16_t* Wf1, uint16_t* Wf2, uint16_t* Wfl,
                           const int* flags){
    int b = blockIdx.x;
    const void* W; uint16_t* Wf; int C, ntiles, lb;
    if (b < 64)        { W = W0; Wf = Wf0; C = 128; ntiles = 8; lb = b; }
    else if (b < 128)  { W = W1; Wf = Wf1; C = 128; ntiles = 8; lb = b - 64; }
    else if (b < 192)  { W = W2; Wf = Wf2; C = 128; ntiles = 8; lb = b - 128; }
    else               { W = Wl; Wf = Wfl; C = 40;  ntiles = 3; lb = b - 192; }
    int idx = lb * 256 + threadIdx.x;
    int total = 4 * ntiles * 512;
    if (idx >= total) return;
    int j = idx & 7;
    int lane = (idx >> 3) & 63;
    int nt = (idx >> 9) % ntiles;
    int kt = idx / (512 * ntiles);
    int k = kt * 32 + (lane >> 4) * 8 + j;
    int n = nt * 16 + (lane & 15);
    uint16_t v = 0;
    if (n < C){
        v = flags[1] ? ((const uint16_t*)W)[k * C + n]
                     : f2b(((const float*)W)[k * C + n]);
    }
    Wf[idx] = v;
}

// ---------- all bias conversions in ONE launch (bc[424]) ----------
__global__ void k_cvt_bias(const void* b0, const void* b1, const void* b2, const void* bl,
                           float* bc, const int* flags){
    int i = blockIdx.x * blockDim.x + threadIdx.x;
    if (i >= 424) return;
    const void* src; int li;
    if (i < 128)      { src = b0; li = i; }
    else if (i < 256) { src = b1; li = i - 128; }
    else if (i < 384) { src = b2; li = i - 256; }
    else              { src = bl; li = i - 384; }
    bc[i] = flags[1] ? b2f(((const uint16_t*)src)[li]) : ((const float*)src)[li];
}

// ---------- aggregation with lazy BN+ReLU on read ----------
// layer 0 (apply_bn=0): input = flags[1] ? xraw : Yin;  layers 1/2: Yin with BN+ReLU.
__global__ __launch_bounds__(256) void k_agg(const uint16_t* __restrict__ Yin,
                                             const uint16_t* __restrict__ xraw,
                                             const int* __restrict__ rp,
                                             const int* __restrict__ col,
                                             uint16_t* __restrict__ out, int N,
                                             const float* __restrict__ st,
                                             int apply_bn, float ninv,
                                             const int* __restrict__ flags){
    int t = threadIdx.x;
    int l16 = t & 15;
    int i = blockIdx.x * 16 + (t >> 4);
    if (i >= N) return;
    float mm[8], iv[8];
    const uint16_t* src = Yin;
    if (apply_bn){
        int f0 = l16 * 8;
        #pragma unroll
        for (int j = 0; j < 8; j++){
            float sv = st[f0 + j];
            float qv = st[128 + f0 + j];
            float m = sv * ninv;
            float var = qv * ninv - m * m;
            mm[j] = m;
            iv[j] = rsqrtf(var + 1e-5f);
        }
    } else if (flags[1]){
        src = xraw;
    }
    const uint4* base = (const uint4*)src;
    float a[8] = {0.f, 0.f, 0.f, 0.f, 0.f, 0.f, 0.f, 0.f};
    int s0 = rp[i], e0 = rp[i + 1];
    for (int k = s0 - 1; k < e0; k++){           // k==s0-1 encodes the self loop
        int j = (k < s0) ? i : col[k];
        uint4 w = base[(size_t)j * 16 + l16];
        float v[8] = {blo(w.x), bhi(w.x), blo(w.y), bhi(w.y),
                      blo(w.z), bhi(w.z), blo(w.w), bhi(w.w)};
        if (apply_bn){
            #pragma unroll
            for (int jj = 0; jj < 8; jj++) v[jj] = fmaxf((v[jj] - mm[jj]) * iv[jj], 0.f);
        }
        #pragma unroll
        for (int jj = 0; jj < 8; jj++) a[jj] += v[jj];
    }
    uint4 o;
    o.x = pack2(a[0], a[1]); o.y = pack2(a[2], a[3]);
    o.z = pack2(a[4], a[5]); o.w = pack2(a[6], a[7]);
    ((uint4*)out)[(size_t)i * 16 + l16] = o;
}

// ---------- MFMA GEMM (in place) + bias + per-block stats partials (NO global atomics) ----------
// 128 rows per block: each wave handles 2 m-tiles (rows base+wave*16 and base+64+wave*16)
__global__ __launch_bounds__(256) void k_gemm(uint16_t* __restrict__ A,
                                              const uint16_t* __restrict__ Wf,
                                              const float* __restrict__ bias,
                                              float* __restrict__ part, int N){
    __shared__ __align__(16) uint16_t wlds[16384];
    __shared__ float sh_sum[128], sh_ssq[128];
    int t = threadIdx.x;
    if (t < 128){ sh_sum[t] = 0.f; sh_ssq[t] = 0.f; }
    {
        const uint4* s = (const uint4*)Wf;
        uint4* d = (uint4*)wlds;
        for (int i = t; i < 2048; i += 256) d[i] = s[i];
    }
    __syncthreads();
    int lane = t & 63, wave = t >> 6;
    int m = lane & 15, q = lane >> 4;
    int rb[2];
    rb[0] = blockIdx.x * 128 + wave * 16;
    rb[1] = rb[0] + 64;
    short8 afrag[2][4];
    #pragma unroll
    for (int mt = 0; mt < 2; mt++){
        int arow = rb[mt] + m;
        if (arow >= N) arow = N - 1;
        const short8* ap = (const short8*)(A + (size_t)arow * 128);
        #pragma unroll
        for (int kt = 0; kt < 4; kt++) afrag[mt][kt] = ap[kt * 4 + q];
    }
    floatx4 acc[2][8];
    #pragma unroll
    for (int mt = 0; mt < 2; mt++)
        #pragma unroll
        for (int nt = 0; nt < 8; nt++) acc[mt][nt] = (floatx4){0.f, 0.f, 0.f, 0.f};
    const short8* wl = (const short8*)wlds;
    #pragma unroll
    for (int kt = 0; kt < 4; kt++){
        #pragma unroll
        for (int nt = 0; nt < 8; nt++){
            short8 bfrag = wl[(kt * 8 + nt) * 64 + lane];
            #pragma unroll
            for (int mt = 0; mt < 2; mt++){
                acc[mt][nt] = __builtin_amdgcn_mfma_f32_16x16x32_bf16(afrag[mt][kt], bfrag, acc[mt][nt], 0, 0, 0);
            }
        }
    }
    #pragma unroll
    for (int mt = 0; mt < 2; mt++){
        #pragma unroll
        for (int nt = 0; nt < 8; nt++){
            int ccol = nt * 16 + m;
            float bv = bias[ccol];
            float s = 0.f, ss = 0.f;
            #pragma unroll
            for (int r = 0; r < 4; r++){
                int grow = rb[mt] + q * 4 + r;
                if (grow < N){
                    float y = acc[mt][nt][r] + bv;
                    A[(size_t)grow * 128 + ccol] = f2b(y);
                    s += y;
                    ss += y * y;
                }
            }
            s += __shfl_xor(s, 16); s += __shfl_xor(s, 32);
            ss += __shfl_xor(ss, 16); ss += __shfl_xor(ss, 32);
            if (q == 0){
                atomicAdd(&sh_sum[ccol], s);
                atomicAdd(&sh_ssq[ccol], ss);
            }
        }
    }
    __syncthreads();
    if (t < 128){
        part[(size_t)blockIdx.x * 256 + t] = sh_sum[t];
        part[(size_t)blockIdx.x * 256 + 128 + t] = sh_ssq[t];
    }
}

// ---------- reduce per-block partials -> st[256] (sum[128], ssq[128]) ----------
__global__ void k_red(const float* __restrict__ part, int nb, float* __restrict__ st){
    int t = threadIdx.x;   // 256
    float s = 0.f;
    for (int b = 0; b < nb; b++) s += part[(size_t)b * 256 + t];
    st[t] = s;
}

// ---------- final GEMM with BN+ReLU applied to A on read ----------
__global__ __launch_bounds__(256) void k_out(const uint16_t* __restrict__ A,
                                             const uint16_t* __restrict__ Wf,
                                             const float* __restrict__ bias,
                                             const float* __restrict__ st, float ninv,
                                             void* __restrict__ out, int N,
                                             const int* __restrict__ flags){
    __shared__ __align__(16) uint16_t wlds[6144];
    __shared__ float s_m[128], s_iv[128];
    int t = threadIdx.x;
    {
        const uint4* s = (const uint4*)Wf;
        uint4* d = (uint4*)wlds;
        for (int i = t; i < 768; i += 256) d[i] = s[i];
    }
    if (t < 128){
        float m = st[t] * ninv;
        float var = st[128 + t] * ninv - m * m;
        s_m[t] = m;
        s_iv[t] = rsqrtf(var + 1e-5f);
    }
    __syncthreads();
    int lane = t & 63, wave = t >> 6;
    int m = lane & 15, q = lane >> 4;
    int row_base = blockIdx.x * 64 + wave * 16;
    int arow = row_base + m;
    if (arow >= N) arow = N - 1;
    short8 afrag[4];
    const uint4* ap = (const uint4*)(A + (size_t)arow * 128);
    #pragma unroll
    for (int kt = 0; kt < 4; kt++){
        uint4 u = ap[kt * 4 + q];
        float v[8] = {blo(u.x), bhi(u.x), blo(u.y), bhi(u.y),
                      blo(u.z), bhi(u.z), blo(u.w), bhi(u.w)};
        int c0 = kt * 32 + q * 8;
        #pragma unroll
        for (int j = 0; j < 8; j++) v[j] = fmaxf((v[j] - s_m[c0 + j]) * s_iv[c0 + j], 0.f);
        uint4 o;
        o.x = pack2(v[0], v[1]); o.y = pack2(v[2], v[3]);
        o.z = pack2(v[4], v[5]); o.w = pack2(v[6], v[7]);
        afrag[kt] = *(short8*)&o;
    }
    floatx4 acc[3];
    #pragma unroll
    for (int nt = 0; nt < 3; nt++) acc[nt] = (floatx4){0.f, 0.f, 0.f, 0.f};
    const short8* wl = (const short8*)wlds;
    #pragma unroll
    for (int kt = 0; kt < 4; kt++){
        #pragma unroll
        for (int nt = 0; nt < 3; nt++){
            acc[nt] = __builtin_amdgcn_mfma_f32_16x16x32_bf16(afrag[kt], wl[(kt * 3 + nt) * 64 + lane], acc[nt], 0, 0, 0);
        }
    }
    int isbf = flags[1];
    #pragma unroll
    for (int nt = 0; nt < 3; nt++){
        int ccol = nt * 16 + m;
        if (ccol < 40){
            float bv = bias[ccol];
            #pragma unroll
            for (int r = 0; r < 4; r++){
                int grow = row_base + q * 4 + r;
                if (grow < N){
                    float y = acc[nt][r] + bv;
                    if (isbf) ((uint16_t*)out)[(size_t)grow * 40 + ccol] = f2b(y);
                    else      ((float*)out)[(size_t)grow * 40 + ccol] = y;
                }
            }
        }
    }
}

extern "C" void kernel_launch(void* const* d_in, const int* in_sizes, int n_in,
                              void* d_out, int out_size, void* d_ws, size_t ws_size,
                              hipStream_t stream){
    (void)n_in;
    const void* x  = d_in[0];
    const int* ei  = (const int*)d_in[1];
    const void* W0 = d_in[2];
    const void* b0 = d_in[3];
    const void* W1 = d_in[4];
    const void* b1 = d_in[5];
    const void* W2 = d_in[6];
    const void* b2 = d_in[7];
    const void* Wl = d_in[8];
    const void* bl = d_in[9];

    const int N = in_sizes[0] / 128;
    const int E = in_sizes[1] / 2;
    const int NF = N * 128;
    const int NB = (N + 255) / 256;
    const int gemm_blocks2 = (N + 127) / 128;   // 128-row blocks
    const int gemm_blocks  = (N + 63) / 64;     // k_out blocks

    // ---- workspace layout ----
    char* ws = (char*)d_ws;
    size_t off = 0;
    uint16_t* hx = (uint16_t*)(ws + off); off += ((size_t)NF * 2 + 255) & ~(size_t)255;
    uint16_t* ag = (uint16_t*)(ws + off); off += ((size_t)NF * 2 + 255) & ~(size_t)255;
    int* col     = (int*)(ws + off);      off += ((size_t)E * 4 + 255) & ~(size_t)255;
    int* rp      = (int*)(ws + off);      off += ((size_t)(N + 1) * 4 + 255) & ~(size_t)255;
    int* cur     = (int*)(ws + off);      off += ((size_t)N * 4 + 255) & ~(size_t)255;
    int* deg     = (int*)(ws + off);      off += ((size_t)N * 4 + 255) & ~(size_t)255;
    int* bsum    = (int*)(ws + off);      off += 512 * 4;
    int* flags   = (int*)(ws + off);      off += 256;
    uint16_t* Wf0 = (uint16_t*)(ws + off); off += 16384 * 2;
    uint16_t* Wf1 = (uint16_t*)(ws + off); off += 16384 * 2;
    uint16_t* Wf2 = (uint16_t*)(ws + off); off += 16384 * 2;
    uint16_t* Wfl = (uint16_t*)(ws + off); off += 6144 * 2;
    float* bc    = (float*)(ws + off);    off += 424 * 4 + 160;
    float* stats = (float*)(ws + off);    off += 768 * 4;   // 3 layers x (sum[128], ssq[128])
    float* part  = (float*)(ws + off);    off += (size_t)gemm_blocks2 * 256 * 4;
    const size_t required = off;

    if (ws_size < required){
        int nwords = out_size / 2;
        k_sentinel<<<(nwords + 255) / 256, 256, 0, stream>>>((uint32_t*)d_out, nwords, 0x40004000u);
        return;
    }

    // ---- flags, zeroing, CSR ----
    k_flags<<<1, 64, 0, stream>>>((const uint32_t*)x, ei, flags);
    k_zero<<<(N + 255) / 256, 256, 0, stream>>>(deg, N);
    k_deg<<<(E + 255) / 256, 256, 0, stream>>>(ei, E, deg, flags);
    k_scan1<<<NB, 256, 0, stream>>>(deg, N, bsum);
    k_scan2<<<1, 512, 0, stream>>>(bsum, NB, rp, N);
    k_scan3<<<NB, 256, 0, stream>>>(deg, N, bsum, rp, cur);
    k_fill<<<(E + 255) / 256, 256, 0, stream>>>(ei, E, cur, col, flags);

    // ---- conversions / weight prep ----
    k_cvt_x<<<(NF + 255) / 256, 256, 0, stream>>>(x, hx, NF, flags);
    k_prep_all<<<216, 256, 0, stream>>>(W0, W1, W2, Wl, Wf0, Wf1, Wf2, Wfl, flags);
    k_cvt_bias<<<2, 256, 0, stream>>>(b0, b1, b2, bl, bc, flags);

    const float ninv = 1.0f / (float)N;
    const int agg_blocks = (N + 15) / 16;
    const uint16_t* xr = (const uint16_t*)x;

    // layer 0: agg(x) -> ag, gemm in place (Y0 in ag), stats0
    k_agg<<<agg_blocks, 256, 0, stream>>>(hx, xr, rp, col, ag, N, stats, 0, ninv, flags);
    k_gemm<<<gemm_blocks2, 256, 0, stream>>>(ag, Wf0, bc, part, N);
    k_red<<<1, 256, 0, stream>>>(part, gemm_blocks2, stats);
    // layer 1: agg(bn0(Y0)) -> hx, gemm in place (Y1 in hx), stats1
    k_agg<<<agg_blocks, 256, 0, stream>>>(ag, xr, rp, col, hx, N, stats, 1, ninv, flags);
    k_gemm<<<gemm_blocks2, 256, 0, stream>>>(hx, Wf1, bc + 128, part, N);
    k_red<<<1, 256, 0, stream>>>(part, gemm_blocks2, stats + 256);
    // layer 2: agg(bn1(Y1)) -> ag, gemm in place (Y2 in ag), stats2
    k_agg<<<agg_blocks, 256, 0, stream>>>(hx, xr, rp, col, ag, N, stats + 256, 1, ninv, flags);
    k_gemm<<<gemm_blocks2, 256, 0, stream>>>(ag, Wf2, bc + 256, part, N);
    k_red<<<1, 256, 0, stream>>>(part, gemm_blocks2, stats + 512);
    // final: out = bn2(Y2)relu @ Wl + bl
    k_out<<<gemm_blocks, 256, 0, stream>>>(ag, Wfl, bc + 384, stats + 512, ninv, d_out, N, flags);
}

// Round 11
// 509.290 us; speedup vs baseline: 1.9634x; 1.9634x over previous
//
#include <hip/hip_runtime.h>
#include <stdint.h>

typedef __attribute__((ext_vector_type(8))) short short8;    // MFMA A/B frag (8 bf16)
typedef __attribute__((ext_vector_type(4))) float floatx4;   // MFMA C/D frag

// ---------- bf16 helpers ----------
static __device__ __forceinline__ float b2f(uint16_t b){
    return __uint_as_float(((uint32_t)b) << 16);
}
static __device__ __forceinline__ uint16_t f2b(float f){
    uint32_t u = __float_as_uint(f);
    return (uint16_t)((u + 0x7fffu + ((u >> 16) & 1u)) >> 16);
}
static __device__ __forceinline__ float blo(uint32_t v){ return __uint_as_float(v << 16); }
static __device__ __forceinline__ float bhi(uint32_t v){ return __uint_as_float(v & 0xffff0000u); }
static __device__ __forceinline__ uint32_t pack2(float a, float b){
    return ((uint32_t)f2b(b) << 16) | (uint32_t)f2b(a);
}

// ---------- sentinel (only used when ws too small) ----------
__global__ void k_sentinel(uint32_t* out, int nwords, uint32_t pat){
    int i = blockIdx.x * blockDim.x + threadIdx.x;
    if (i < nwords) out[i] = pat;
}

// ---------- dtype flags: flags[0]=edge_is_int64, flags[1]=x_is_bf16 ----------
__global__ void k_flags(const uint32_t* xw, const int* ei, int* flags){
    if (threadIdx.x != 0 || blockIdx.x != 0) return;
    int odd_nz = 0;
    for (int k = 0; k < 128; k++){
        if (ei[2 * k + 1] != 0) odd_nz = 1;
    }
    flags[0] = odd_nz ? 0 : 1;
    int big = 0;
    for (int k = 0; k < 128; k++){
        float lo = __uint_as_float(xw[k] << 16);
        if (!(fabsf(lo) <= 1024.0f)) big = 1;
    }
    flags[1] = big ? 0 : 1;
}

// ---------- zero deg[N] ----------
__global__ void k_zero(int* deg, int N){
    int i = blockIdx.x * blockDim.x + threadIdx.x;
    if (i < N) deg[i] = 0;
}

// ---------- CSR build ----------
__global__ void k_deg(const int* ei, int E, int* deg, const int* flags){
    int e = blockIdx.x * blockDim.x + threadIdx.x;
    if (e < E){
        int d = flags[0] ? ei[2 * e] : ei[e];
        atomicAdd(&deg[d], 1);
    }
}

__global__ void k_scan1(const int* deg, int N, int* bsum){
    __shared__ int s[256];
    int t = threadIdx.x;
    int i = blockIdx.x * 256 + t;
    s[t] = (i < N) ? deg[i] : 0;
    __syncthreads();
    for (int off = 128; off > 0; off >>= 1){
        if (t < off) s[t] += s[t + off];
        __syncthreads();
    }
    if (t == 0) bsum[blockIdx.x] = s[0];
}

__global__ void k_scan2(int* bsum, int nb, int* rp, int N){
    __shared__ int s[512];
    int t = threadIdx.x;
    int v = (t < nb) ? bsum[t] : 0;
    s[t] = v;
    __syncthreads();
    for (int off = 1; off < 512; off <<= 1){
        int u = (t >= off) ? s[t - off] : 0;
        __syncthreads();
        s[t] += u;
        __syncthreads();
    }
    if (t < nb) bsum[t] = s[t] - v;
    if (t == 511) rp[N] = s[511];
}

__global__ void k_scan3(const int* deg, int N, const int* bpre, int* rp, int* cur){
    __shared__ int s[256];
    int t = threadIdx.x;
    int i = blockIdx.x * 256 + t;
    int v = (i < N) ? deg[i] : 0;
    s[t] = v;
    __syncthreads();
    for (int off = 1; off < 256; off <<= 1){
        int u = (t >= off) ? s[t - off] : 0;
        __syncthreads();
        s[t] += u;
        __syncthreads();
    }
    if (i < N){
        int ex = bpre[blockIdx.x] + s[t] - v;
        rp[i] = ex;
        cur[i] = ex;
    }
}

__global__ void k_fill(const int* ei, int E, int* cur, int* col, const int* flags){
    int e = blockIdx.x * blockDim.x + threadIdx.x;
    if (e < E){
        int is64 = flags[0];
        int d = is64 ? ei[2 * e] : ei[e];
        int sv = is64 ? ei[2 * (E + e)] : ei[E + e];
        int p = atomicAdd(&cur[d], 1);
        col[p] = sv;
    }
}

// ---------- input conversion (early-out when x already bf16) ----------
__global__ void k_cvt_x(const void* x, uint16_t* hx, int n, const int* flags){
    if (flags[1]) return;   // layer-0 k_agg reads raw x directly in bf16 case
    int i = blockIdx.x * blockDim.x + threadIdx.x;
    if (i >= n) return;
    hx[i] = f2b(((const float*)x)[i]);
}

// ---------- all W fragment reorders in ONE launch ----------
__global__ void k_prep_all(const void* W0, const void* W1, const void* W2, const void* Wl,
                           uint16_t* Wf0, uint16_t* Wf1, uint16_t* Wf2, uint16_t* Wfl,
                           const int* flags){
    int b = blockIdx.x;
    const void* W; uint16_t* Wf; int C, ntiles, lb;
    if (b < 64)        { W = W0; Wf = Wf0; C = 128; ntiles = 8; lb = b; }
    else if (b < 128)  { W = W1; Wf = Wf1; C = 128; ntiles = 8; lb = b - 64; }
    else if (b < 192)  { W = W2; Wf = Wf2; C = 128; ntiles = 8; lb = b - 128; }
    else               { W = Wl; Wf = Wfl; C = 40;  ntiles = 3; lb = b - 192; }
    int idx = lb * 256 + threadIdx.x;
    int total = 4 * ntiles * 512;
    if (idx >= total) return;
    int j = idx & 7;
    int lane = (idx >> 3) & 63;
    int nt = (idx >> 9) % ntiles;
    int kt = idx / (512 * ntiles);
    int k = kt * 32 + (lane >> 4) * 8 + j;
    int n = nt * 16 + (lane & 15);
    uint16_t v = 0;
    if (n < C){
        v = flags[1] ? ((const uint16_t*)W)[k * C + n]
                     : f2b(((const float*)W)[k * C + n]);
    }
    Wf[idx] = v;
}

// ---------- all bias conversions in ONE launch (bc[424]) ----------
__global__ void k_cvt_bias(const void* b0, const void* b1, const void* b2, const void* bl,
                           float* bc, const int* flags){
    int i = blockIdx.x * blockDim.x + threadIdx.x;
    if (i >= 424) return;
    const void* src; int li;
    if (i < 128)      { src = b0; li = i; }
    else if (i < 256) { src = b1; li = i - 128; }
    else if (i < 384) { src = b2; li = i - 256; }
    else              { src = bl; li = i - 384; }
    bc[i] = flags[1] ? b2f(((const uint16_t*)src)[li]) : ((const float*)src)[li];
}

// ---------- aggregation with lazy BN+ReLU on read ----------
// layer 0 (apply_bn=0): input = flags[1] ? xraw : Yin;  layers 1/2: Yin with BN+ReLU.
__global__ __launch_bounds__(256) void k_agg(const uint16_t* __restrict__ Yin,
                                             const uint16_t* __restrict__ xraw,
                                             const int* __restrict__ rp,
                                             const int* __restrict__ col,
                                             uint16_t* __restrict__ out, int N,
                                             const float* __restrict__ st,
                                             int apply_bn, float ninv,
                                             const int* __restrict__ flags){
    int t = threadIdx.x;
    int l16 = t & 15;
    int i = blockIdx.x * 16 + (t >> 4);
    if (i >= N) return;
    float mm[8], iv[8];
    const uint16_t* src = Yin;
    if (apply_bn){
        int f0 = l16 * 8;
        #pragma unroll
        for (int j = 0; j < 8; j++){
            float sv = st[f0 + j];
            float qv = st[128 + f0 + j];
            float m = sv * ninv;
            float var = qv * ninv - m * m;
            mm[j] = m;
            iv[j] = rsqrtf(var + 1e-5f);
        }
    } else if (flags[1]){
        src = xraw;
    }
    const uint4* base = (const uint4*)src;
    float a[8] = {0.f, 0.f, 0.f, 0.f, 0.f, 0.f, 0.f, 0.f};
    int s0 = rp[i], e0 = rp[i + 1];
    for (int k = s0 - 1; k < e0; k++){           // k==s0-1 encodes the self loop
        int j = (k < s0) ? i : col[k];
        uint4 w = base[(size_t)j * 16 + l16];
        float v[8] = {blo(w.x), bhi(w.x), blo(w.y), bhi(w.y),
                      blo(w.z), bhi(w.z), blo(w.w), bhi(w.w)};
        if (apply_bn){
            #pragma unroll
            for (int jj = 0; jj < 8; jj++) v[jj] = fmaxf((v[jj] - mm[jj]) * iv[jj], 0.f);
        }
        #pragma unroll
        for (int jj = 0; jj < 8; jj++) a[jj] += v[jj];
    }
    uint4 o;
    o.x = pack2(a[0], a[1]); o.y = pack2(a[2], a[3]);
    o.z = pack2(a[4], a[5]); o.w = pack2(a[6], a[7]);
    ((uint4*)out)[(size_t)i * 16 + l16] = o;
}

// ---------- MFMA GEMM (in place) + bias + per-block stats partials (NO global atomics) ----------
// 128 rows per block: each wave handles 2 m-tiles (rows base+wave*16 and base+64+wave*16)
__global__ __launch_bounds__(256) void k_gemm(uint16_t* __restrict__ A,
                                              const uint16_t* __restrict__ Wf,
                                              const float* __restrict__ bias,
                                              float* __restrict__ part, int N){
    __shared__ __align__(16) uint16_t wlds[16384];
    __shared__ float sh_sum[128], sh_ssq[128];
    int t = threadIdx.x;
    if (t < 128){ sh_sum[t] = 0.f; sh_ssq[t] = 0.f; }
    {
        const uint4* s = (const uint4*)Wf;
        uint4* d = (uint4*)wlds;
        for (int i = t; i < 2048; i += 256) d[i] = s[i];
    }
    __syncthreads();
    int lane = t & 63, wave = t >> 6;
    int m = lane & 15, q = lane >> 4;
    int rb[2];
    rb[0] = blockIdx.x * 128 + wave * 16;
    rb[1] = rb[0] + 64;
    short8 afrag[2][4];
    #pragma unroll
    for (int mt = 0; mt < 2; mt++){
        int arow = rb[mt] + m;
        if (arow >= N) arow = N - 1;
        const short8* ap = (const short8*)(A + (size_t)arow * 128);
        #pragma unroll
        for (int kt = 0; kt < 4; kt++) afrag[mt][kt] = ap[kt * 4 + q];
    }
    floatx4 acc[2][8];
    #pragma unroll
    for (int mt = 0; mt < 2; mt++)
        #pragma unroll
        for (int nt = 0; nt < 8; nt++) acc[mt][nt] = (floatx4){0.f, 0.f, 0.f, 0.f};
    const short8* wl = (const short8*)wlds;
    #pragma unroll
    for (int kt = 0; kt < 4; kt++){
        #pragma unroll
        for (int nt = 0; nt < 8; nt++){
            short8 bfrag = wl[(kt * 8 + nt) * 64 + lane];
            #pragma unroll
            for (int mt = 0; mt < 2; mt++){
                acc[mt][nt] = __builtin_amdgcn_mfma_f32_16x16x32_bf16(afrag[mt][kt], bfrag, acc[mt][nt], 0, 0, 0);
            }
        }
    }
    #pragma unroll
    for (int mt = 0; mt < 2; mt++){
        #pragma unroll
        for (int nt = 0; nt < 8; nt++){
            int ccol = nt * 16 + m;
            float bv = bias[ccol];
            float s = 0.f, ss = 0.f;
            #pragma unroll
            for (int r = 0; r < 4; r++){
                int grow = rb[mt] + q * 4 + r;
                if (grow < N){
                    float y = acc[mt][nt][r] + bv;
                    A[(size_t)grow * 128 + ccol] = f2b(y);
                    s += y;
                    ss += y * y;
                }
            }
            s += __shfl_xor(s, 16); s += __shfl_xor(s, 32);
            ss += __shfl_xor(ss, 16); ss += __shfl_xor(ss, 32);
            if (q == 0){
                atomicAdd(&sh_sum[ccol], s);
                atomicAdd(&sh_ssq[ccol], ss);
            }
        }
    }
    __syncthreads();
    if (t < 128){
        part[(size_t)blockIdx.x * 256 + t] = sh_sum[t];
        part[(size_t)blockIdx.x * 256 + 128 + t] = sh_ssq[t];
    }
}

// ---------- reduce per-block partials -> st[256] (sum[128], ssq[128]) ----------
// v2: 1024 threads (16 waves), 4 segments per column, 4-accumulator unroll for load ILP
__global__ __launch_bounds__(1024) void k_red(const float* __restrict__ part, int nb,
                                              float* __restrict__ st){
    __shared__ float sh[1024];
    int t = threadIdx.x;
    int col = t & 255;
    int seg = t >> 8;               // 0..3
    float s0 = 0.f, s1 = 0.f, s2 = 0.f, s3 = 0.f;
    int b = seg;
    for (; b + 12 < nb; b += 16){   // 4 independent loads in flight per iteration
        s0 += part[(size_t)b * 256 + col];
        s1 += part[(size_t)(b + 4) * 256 + col];
        s2 += part[(size_t)(b + 8) * 256 + col];
        s3 += part[(size_t)(b + 12) * 256 + col];
    }
    for (; b < nb; b += 4) s0 += part[(size_t)b * 256 + col];
    sh[t] = (s0 + s1) + (s2 + s3);
    __syncthreads();
    if (t < 256) st[t] = (sh[t] + sh[t + 256]) + (sh[t + 512] + sh[t + 768]);
}

// ---------- final GEMM with BN+ReLU applied to A on read ----------
__global__ __launch_bounds__(256) void k_out(const uint16_t* __restrict__ A,
                                             const uint16_t* __restrict__ Wf,
                                             const float* __restrict__ bias,
                                             const float* __restrict__ st, float ninv,
                                             void* __restrict__ out, int N,
                                             const int* __restrict__ flags){
    __shared__ __align__(16) uint16_t wlds[6144];
    __shared__ float s_m[128], s_iv[128];
    int t = threadIdx.x;
    {
        const uint4* s = (const uint4*)Wf;
        uint4* d = (uint4*)wlds;
        for (int i = t; i < 768; i += 256) d[i] = s[i];
    }
    if (t < 128){
        float m = st[t] * ninv;
        float var = st[128 + t] * ninv - m * m;
        s_m[t] = m;
        s_iv[t] = rsqrtf(var + 1e-5f);
    }
    __syncthreads();
    int lane = t & 63, wave = t >> 6;
    int m = lane & 15, q = lane >> 4;
    int row_base = blockIdx.x * 64 + wave * 16;
    int arow = row_base + m;
    if (arow >= N) arow = N - 1;
    short8 afrag[4];
    const uint4* ap = (const uint4*)(A + (size_t)arow * 128);
    #pragma unroll
    for (int kt = 0; kt < 4; kt++){
        uint4 u = ap[kt * 4 + q];
        float v[8] = {blo(u.x), bhi(u.x), blo(u.y), bhi(u.y),
                      blo(u.z), bhi(u.z), blo(u.w), bhi(u.w)};
        int c0 = kt * 32 + q * 8;
        #pragma unroll
        for (int j = 0; j < 8; j++) v[j] = fmaxf((v[j] - s_m[c0 + j]) * s_iv[c0 + j], 0.f);
        uint4 o;
        o.x = pack2(v[0], v[1]); o.y = pack2(v[2], v[3]);
        o.z = pack2(v[4], v[5]); o.w = pack2(v[6], v[7]);
        afrag[kt] = *(short8*)&o;
    }
    floatx4 acc[3];
    #pragma unroll
    for (int nt = 0; nt < 3; nt++) acc[nt] = (floatx4){0.f, 0.f, 0.f, 0.f};
    const short8* wl = (const short8*)wlds;
    #pragma unroll
    for (int kt = 0; kt < 4; kt++){
        #pragma unroll
        for (int nt = 0; nt < 3; nt++){
            acc[nt] = __builtin_amdgcn_mfma_f32_16x16x32_bf16(afrag[kt], wl[(kt * 3 + nt) * 64 + lane], acc[nt], 0, 0, 0);
        }
    }
    int isbf = flags[1];
    #pragma unroll
    for (int nt = 0; nt < 3; nt++){
        int ccol = nt * 16 + m;
        if (ccol < 40){
            float bv = bias[ccol];
            #pragma unroll
            for (int r = 0; r < 4; r++){
                int grow = row_base + q * 4 + r;
                if (grow < N){
                    float y = acc[nt][r] + bv;
                    if (isbf) ((uint16_t*)out)[(size_t)grow * 40 + ccol] = f2b(y);
                    else      ((float*)out)[(size_t)grow * 40 + ccol] = y;
                }
            }
        }
    }
}

extern "C" void kernel_launch(void* const* d_in, const int* in_sizes, int n_in,
                              void* d_out, int out_size, void* d_ws, size_t ws_size,
                              hipStream_t stream){
    (void)n_in;
    const void* x  = d_in[0];
    const int* ei  = (const int*)d_in[1];
    const void* W0 = d_in[2];
    const void* b0 = d_in[3];
    const void* W1 = d_in[4];
    const void* b1 = d_in[5];
    const void* W2 = d_in[6];
    const void* b2 = d_in[7];
    const void* Wl = d_in[8];
    const void* bl = d_in[9];

    const int N = in_sizes[0] / 128;
    const int E = in_sizes[1] / 2;
    const int NF = N * 128;
    const int NB = (N + 255) / 256;
    const int gemm_blocks2 = (N + 127) / 128;   // 128-row blocks
    const int gemm_blocks  = (N + 63) / 64;     // k_out blocks

    // ---- workspace layout ----
    char* ws = (char*)d_ws;
    size_t off = 0;
    uint16_t* hx = (uint16_t*)(ws + off); off += ((size_t)NF * 2 + 255) & ~(size_t)255;
    uint16_t* ag = (uint16_t*)(ws + off); off += ((size_t)NF * 2 + 255) & ~(size_t)255;
    int* col     = (int*)(ws + off);      off += ((size_t)E * 4 + 255) & ~(size_t)255;
    int* rp      = (int*)(ws + off);      off += ((size_t)(N + 1) * 4 + 255) & ~(size_t)255;
    int* cur     = (int*)(ws + off);      off += ((size_t)N * 4 + 255) & ~(size_t)255;
    int* deg     = (int*)(ws + off);      off += ((size_t)N * 4 + 255) & ~(size_t)255;
    int* bsum    = (int*)(ws + off);      off += 512 * 4;
    int* flags   = (int*)(ws + off);      off += 256;
    uint16_t* Wf0 = (uint16_t*)(ws + off); off += 16384 * 2;
    uint16_t* Wf1 = (uint16_t*)(ws + off); off += 16384 * 2;
    uint16_t* Wf2 = (uint16_t*)(ws + off); off += 16384 * 2;
    uint16_t* Wfl = (uint16_t*)(ws + off); off += 6144 * 2;
    float* bc    = (float*)(ws + off);    off += 424 * 4 + 160;
    float* stats = (float*)(ws + off);    off += 768 * 4;   // 3 layers x (sum[128], ssq[128])
    float* part  = (float*)(ws + off);    off += (size_t)gemm_blocks2 * 256 * 4;
    const size_t required = off;

    if (ws_size < required){
        int nwords = out_size / 2;
        k_sentinel<<<(nwords + 255) / 256, 256, 0, stream>>>((uint32_t*)d_out, nwords, 0x40004000u);
        return;
    }

    // ---- flags, zeroing, CSR ----
    k_flags<<<1, 64, 0, stream>>>((const uint32_t*)x, ei, flags);
    k_zero<<<(N + 255) / 256, 256, 0, stream>>>(deg, N);
    k_deg<<<(E + 255) / 256, 256, 0, stream>>>(ei, E, deg, flags);
    k_scan1<<<NB, 256, 0, stream>>>(deg, N, bsum);
    k_scan2<<<1, 512, 0, stream>>>(bsum, NB, rp, N);
    k_scan3<<<NB, 256, 0, stream>>>(deg, N, bsum, rp, cur);
    k_fill<<<(E + 255) / 256, 256, 0, stream>>>(ei, E, cur, col, flags);

    // ---- conversions / weight prep ----
    k_cvt_x<<<(NF + 255) / 256, 256, 0, stream>>>(x, hx, NF, flags);
    k_prep_all<<<216, 256, 0, stream>>>(W0, W1, W2, Wl, Wf0, Wf1, Wf2, Wfl, flags);
    k_cvt_bias<<<2, 256, 0, stream>>>(b0, b1, b2, bl, bc, flags);

    const float ninv = 1.0f / (float)N;
    const int agg_blocks = (N + 15) / 16;
    const uint16_t* xr = (const uint16_t*)x;

    // layer 0: agg(x) -> ag, gemm in place (Y0 in ag), stats0
    k_agg<<<agg_blocks, 256, 0, stream>>>(hx, xr, rp, col, ag, N, stats, 0, ninv, flags);
    k_gemm<<<gemm_blocks2, 256, 0, stream>>>(ag, Wf0, bc, part, N);
    k_red<<<1, 1024, 0, stream>>>(part, gemm_blocks2, stats);
    // layer 1: agg(bn0(Y0)) -> hx, gemm in place (Y1 in hx), stats1
    k_agg<<<agg_blocks, 256, 0, stream>>>(ag, xr, rp, col, hx, N, stats, 1, ninv, flags);
    k_gemm<<<gemm_blocks2, 256, 0, stream>>>(hx, Wf1, bc + 128, part, N);
    k_red<<<1, 1024, 0, stream>>>(part, gemm_blocks2, stats + 256);
    // layer 2: agg(bn1(Y1)) -> ag, gemm in place (Y2 in ag), stats2
    k_agg<<<agg_blocks, 256, 0, stream>>>(hx, xr, rp, col, ag, N, stats + 256, 1, ninv, flags);
    k_gemm<<<gemm_blocks2, 256, 0, stream>>>(ag, Wf2, bc + 256, part, N);
    k_red<<<1, 1024, 0, stream>>>(part, gemm_blocks2, stats + 512);
    // final: out = bn2(Y2)relu @ Wl + bl
    k_out<<<gemm_blocks, 256, 0, stream>>>(ag, Wfl, bc + 384, stats + 512, ninv, d_out, N, flags);
}

// Round 12
// 487.907 us; speedup vs baseline: 2.0495x; 1.0438x over previous
//
#include <hip/hip_runtime.h>
#include <stdint.h>

typedef __attribute__((ext_vector_type(8))) short short8;    // MFMA A/B frag (8 bf16)
typedef __attribute__((ext_vector_type(4))) float floatx4;   // MFMA C/D frag

// ---------- bf16 helpers ----------
static __device__ __forceinline__ float b2f(uint16_t b){
    return __uint_as_float(((uint32_t)b) << 16);
}
static __device__ __forceinline__ uint16_t f2b(float f){
    uint32_t u = __float_as_uint(f);
    return (uint16_t)((u + 0x7fffu + ((u >> 16) & 1u)) >> 16);
}
static __device__ __forceinline__ float blo(uint32_t v){ return __uint_as_float(v << 16); }
static __device__ __forceinline__ float bhi(uint32_t v){ return __uint_as_float(v & 0xffff0000u); }
static __device__ __forceinline__ uint32_t pack2(float a, float b){
    return ((uint32_t)f2b(b) << 16) | (uint32_t)f2b(a);
}

// ---------- sentinel (only used when ws too small) ----------
__global__ void k_sentinel(uint32_t* out, int nwords, uint32_t pat){
    int i = blockIdx.x * blockDim.x + threadIdx.x;
    if (i < nwords) out[i] = pat;
}

// ---------- dtype flags: flags[0]=edge_is_int64, flags[1]=x_is_bf16 ----------
__global__ void k_flags(const uint32_t* xw, const int* ei, int* flags){
    if (threadIdx.x != 0 || blockIdx.x != 0) return;
    int odd_nz = 0;
    for (int k = 0; k < 128; k++){
        if (ei[2 * k + 1] != 0) odd_nz = 1;
    }
    flags[0] = odd_nz ? 0 : 1;
    int big = 0;
    for (int k = 0; k < 128; k++){
        float lo = __uint_as_float(xw[k] << 16);
        if (!(fabsf(lo) <= 1024.0f)) big = 1;
    }
    flags[1] = big ? 0 : 1;
}

// ---------- zero deg[N] ----------
__global__ void k_zero(int* deg, int N){
    int i = blockIdx.x * blockDim.x + threadIdx.x;
    if (i < N) deg[i] = 0;
}

// ---------- CSR build ----------
__global__ void k_deg(const int* ei, int E, int* deg, const int* flags){
    int e = blockIdx.x * blockDim.x + threadIdx.x;
    if (e < E){
        int d = flags[0] ? ei[2 * e] : ei[e];
        atomicAdd(&deg[d], 1);
    }
}

__global__ void k_scan1(const int* deg, int N, int* bsum){
    __shared__ int s[256];
    int t = threadIdx.x;
    int i = blockIdx.x * 256 + t;
    s[t] = (i < N) ? deg[i] : 0;
    __syncthreads();
    for (int off = 128; off > 0; off >>= 1){
        if (t < off) s[t] += s[t + off];
        __syncthreads();
    }
    if (t == 0) bsum[blockIdx.x] = s[0];
}

__global__ void k_scan2(int* bsum, int nb, int* rp, int N){
    __shared__ int s[512];
    int t = threadIdx.x;
    int v = (t < nb) ? bsum[t] : 0;
    s[t] = v;
    __syncthreads();
    for (int off = 1; off < 512; off <<= 1){
        int u = (t >= off) ? s[t - off] : 0;
        __syncthreads();
        s[t] += u;
        __syncthreads();
    }
    if (t < nb) bsum[t] = s[t] - v;
    if (t == 511) rp[N] = s[511];
}

__global__ void k_scan3(const int* deg, int N, const int* bpre, int* rp, int* cur){
    __shared__ int s[256];
    int t = threadIdx.x;
    int i = blockIdx.x * 256 + t;
    int v = (i < N) ? deg[i] : 0;
    s[t] = v;
    __syncthreads();
    for (int off = 1; off < 256; off <<= 1){
        int u = (t >= off) ? s[t - off] : 0;
        __syncthreads();
        s[t] += u;
        __syncthreads();
    }
    if (i < N){
        int ex = bpre[blockIdx.x] + s[t] - v;
        rp[i] = ex;
        cur[i] = ex;
    }
}

__global__ void k_fill(const int* ei, int E, int* cur, int* col, const int* flags){
    int e = blockIdx.x * blockDim.x + threadIdx.x;
    if (e < E){
        int is64 = flags[0];
        int d = is64 ? ei[2 * e] : ei[e];
        int sv = is64 ? ei[2 * (E + e)] : ei[E + e];
        int p = atomicAdd(&cur[d], 1);
        __builtin_nontemporal_store(sv, &col[p]);
    }
}

// ---------- input conversion (grid-stride; fast exit when x already bf16) ----------
__global__ void k_cvt_x(const void* x, uint16_t* hx, int n, const int* flags){
    if (flags[1]) return;   // layer-0 k_agg reads raw x directly in bf16 case
    for (int i = blockIdx.x * blockDim.x + threadIdx.x; i < n; i += gridDim.x * blockDim.x)
        hx[i] = f2b(((const float*)x)[i]);
}

// ---------- all W fragment reorders in ONE launch ----------
__global__ void k_prep_all(const void* W0, const void* W1, const void* W2, const void* Wl,
                           uint16_t* Wf0, uint16_t* Wf1, uint16_t* Wf2, uint16_t* Wfl,
                           const int* flags){
    int b = blockIdx.x;
    const void* W; uint16_t* Wf; int C, ntiles, lb;
    if (b < 64)        { W = W0; Wf = Wf0; C = 128; ntiles = 8; lb = b; }
    else if (b < 128)  { W = W1; Wf = Wf1; C = 128; ntiles = 8; lb = b - 64; }
    else if (b < 192)  { W = W2; Wf = Wf2; C = 128; ntiles = 8; lb = b - 128; }
    else               { W = Wl; Wf = Wfl; C = 40;  ntiles = 3; lb = b - 192; }
    int idx = lb * 256 + threadIdx.x;
    int total = 4 * ntiles * 512;
    if (idx >= total) return;
    int j = idx & 7;
    int lane = (idx >> 3) & 63;
    int nt = (idx >> 9) % ntiles;
    int kt = idx / (512 * ntiles);
    int k = kt * 32 + (lane >> 4) * 8 + j;
    int n = nt * 16 + (lane & 15);
    uint16_t v = 0;
    if (n < C){
        v = flags[1] ? ((const uint16_t*)W)[k * C + n]
                     : f2b(((const float*)W)[k * C + n]);
    }
    Wf[idx] = v;
}

// ---------- all bias conversions in ONE launch (bc[424]) ----------
__global__ void k_cvt_bias(const void* b0, const void* b1, const void* b2, const void* bl,
                           float* bc, const int* flags){
    int i = blockIdx.x * blockDim.x + threadIdx.x;
    if (i >= 424) return;
    const void* src; int li;
    if (i < 128)      { src = b0; li = i; }
    else if (i < 256) { src = b1; li = i - 128; }
    else if (i < 384) { src = b2; li = i - 256; }
    else              { src = bl; li = i - 384; }
    bc[i] = flags[1] ? b2f(((const uint16_t*)src)[li]) : ((const float*)src)[li];
}

// ---------- aggregation with lazy BN+ReLU on read (4x unrolled, self-loop peeled) ----------
__global__ __launch_bounds__(256) void k_agg(const uint16_t* __restrict__ Yin,
                                             const uint16_t* __restrict__ xraw,
                                             const int* __restrict__ rp,
                                             const int* __restrict__ col,
                                             uint16_t* __restrict__ out, int N,
                                             const float* __restrict__ st,
                                             int apply_bn, float ninv,
                                             const int* __restrict__ flags){
    int t = threadIdx.x;
    int l16 = t & 15;
    int i = blockIdx.x * 16 + (t >> 4);
    if (i >= N) return;
    float mm[8], iv[8];
    const uint16_t* src = Yin;
    if (apply_bn){
        int f0 = l16 * 8;
        #pragma unroll
        for (int j = 0; j < 8; j++){
            float sv = st[f0 + j];
            float qv = st[128 + f0 + j];
            float m = sv * ninv;
            float var = qv * ninv - m * m;
            mm[j] = m;
            iv[j] = rsqrtf(var + 1e-5f);
        }
    } else if (flags[1]){
        src = xraw;
    }
    const uint4* base = (const uint4*)src;
    int s0 = rp[i], e0 = rp[i + 1];
    float a[8];
    {   // self loop (peeled out of the neighbor loop)
        uint4 w = base[(size_t)i * 16 + l16];
        a[0] = blo(w.x); a[1] = bhi(w.x); a[2] = blo(w.y); a[3] = bhi(w.y);
        a[4] = blo(w.z); a[5] = bhi(w.z); a[6] = blo(w.w); a[7] = bhi(w.w);
        if (apply_bn){
            #pragma unroll
            for (int jj = 0; jj < 8; jj++) a[jj] = fmaxf((a[jj] - mm[jj]) * iv[jj], 0.f);
        }
    }
    int k = s0;
    for (; k + 3 < e0; k += 4){     // 4 independent row gathers in flight
        int j0 = col[k], j1 = col[k + 1], j2 = col[k + 2], j3 = col[k + 3];
        uint4 ww[4];
        ww[0] = base[(size_t)j0 * 16 + l16];
        ww[1] = base[(size_t)j1 * 16 + l16];
        ww[2] = base[(size_t)j2 * 16 + l16];
        ww[3] = base[(size_t)j3 * 16 + l16];
        #pragma unroll
        for (int u = 0; u < 4; u++){
            float v[8] = {blo(ww[u].x), bhi(ww[u].x), blo(ww[u].y), bhi(ww[u].y),
                          blo(ww[u].z), bhi(ww[u].z), blo(ww[u].w), bhi(ww[u].w)};
            if (apply_bn){
                #pragma unroll
                for (int jj = 0; jj < 8; jj++) v[jj] = fmaxf((v[jj] - mm[jj]) * iv[jj], 0.f);
            }
            #pragma unroll
            for (int jj = 0; jj < 8; jj++) a[jj] += v[jj];
        }
    }
    for (; k < e0; k++){            // remainder 0..3 edges
        int j = col[k];
        uint4 w = base[(size_t)j * 16 + l16];
        float v[8] = {blo(w.x), bhi(w.x), blo(w.y), bhi(w.y),
                      blo(w.z), bhi(w.z), blo(w.w), bhi(w.w)};
        if (apply_bn){
            #pragma unroll
            for (int jj = 0; jj < 8; jj++) v[jj] = fmaxf((v[jj] - mm[jj]) * iv[jj], 0.f);
        }
        #pragma unroll
        for (int jj = 0; jj < 8; jj++) a[jj] += v[jj];
    }
    uint4 o;
    o.x = pack2(a[0], a[1]); o.y = pack2(a[2], a[3]);
    o.z = pack2(a[4], a[5]); o.w = pack2(a[6], a[7]);
    ((uint4*)out)[(size_t)i * 16 + l16] = o;
}

// ---------- MFMA GEMM (in place) + bias + per-block stats partials (NO global atomics) ----------
// 128 rows per block: each wave handles 2 m-tiles (rows base+wave*16 and base+64+wave*16)
__global__ __launch_bounds__(256) void k_gemm(uint16_t* __restrict__ A,
                                              const uint16_t* __restrict__ Wf,
                                              const float* __restrict__ bias,
                                              float* __restrict__ part, int N){
    __shared__ __align__(16) uint16_t wlds[16384];
    __shared__ float sh_sum[128], sh_ssq[128];
    int t = threadIdx.x;
    if (t < 128){ sh_sum[t] = 0.f; sh_ssq[t] = 0.f; }
    {
        const uint4* s = (const uint4*)Wf;
        uint4* d = (uint4*)wlds;
        for (int i = t; i < 2048; i += 256) d[i] = s[i];
    }
    __syncthreads();
    int lane = t & 63, wave = t >> 6;
    int m = lane & 15, q = lane >> 4;
    int rb[2];
    rb[0] = blockIdx.x * 128 + wave * 16;
    rb[1] = rb[0] + 64;
    short8 afrag[2][4];
    #pragma unroll
    for (int mt = 0; mt < 2; mt++){
        int arow = rb[mt] + m;
        if (arow >= N) arow = N - 1;
        const short8* ap = (const short8*)(A + (size_t)arow * 128);
        #pragma unroll
        for (int kt = 0; kt < 4; kt++) afrag[mt][kt] = ap[kt * 4 + q];
    }
    floatx4 acc[2][8];
    #pragma unroll
    for (int mt = 0; mt < 2; mt++)
        #pragma unroll
        for (int nt = 0; nt < 8; nt++) acc[mt][nt] = (floatx4){0.f, 0.f, 0.f, 0.f};
    const short8* wl = (const short8*)wlds;
    #pragma unroll
    for (int kt = 0; kt < 4; kt++){
        #pragma unroll
        for (int nt = 0; nt < 8; nt++){
            short8 bfrag = wl[(kt * 8 + nt) * 64 + lane];
            #pragma unroll
            for (int mt = 0; mt < 2; mt++){
                acc[mt][nt] = __builtin_amdgcn_mfma_f32_16x16x32_bf16(afrag[mt][kt], bfrag, acc[mt][nt], 0, 0, 0);
            }
        }
    }
    #pragma unroll
    for (int mt = 0; mt < 2; mt++){
        #pragma unroll
        for (int nt = 0; nt < 8; nt++){
            int ccol = nt * 16 + m;
            float bv = bias[ccol];
            float s = 0.f, ss = 0.f;
            #pragma unroll
            for (int r = 0; r < 4; r++){
                int grow = rb[mt] + q * 4 + r;
                if (grow < N){
                    float y = acc[mt][nt][r] + bv;
                    A[(size_t)grow * 128 + ccol] = f2b(y);
                    s += y;
                    ss += y * y;
                }
            }
            s += __shfl_xor(s, 16); s += __shfl_xor(s, 32);
            ss += __shfl_xor(ss, 16); ss += __shfl_xor(ss, 32);
            if (q == 0){
                atomicAdd(&sh_sum[ccol], s);
                atomicAdd(&sh_ssq[ccol], ss);
            }
        }
    }
    __syncthreads();
    if (t < 128){
        part[(size_t)blockIdx.x * 256 + t] = sh_sum[t];
        part[(size_t)blockIdx.x * 256 + 128 + t] = sh_ssq[t];
    }
}

// ---------- reduce per-block partials -> st[256] (sum[128], ssq[128]) ----------
// 1024 threads (16 waves), 4 segments per column, 4-accumulator unroll for load ILP
__global__ __launch_bounds__(1024) void k_red(const float* __restrict__ part, int nb,
                                              float* __restrict__ st){
    __shared__ float sh[1024];
    int t = threadIdx.x;
    int col = t & 255;
    int seg = t >> 8;               // 0..3
    float s0 = 0.f, s1 = 0.f, s2 = 0.f, s3 = 0.f;
    int b = seg;
    for (; b + 12 < nb; b += 16){   // 4 independent loads in flight per iteration
        s0 += part[(size_t)b * 256 + col];
        s1 += part[(size_t)(b + 4) * 256 + col];
        s2 += part[(size_t)(b + 8) * 256 + col];
        s3 += part[(size_t)(b + 12) * 256 + col];
    }
    for (; b < nb; b += 4) s0 += part[(size_t)b * 256 + col];
    sh[t] = (s0 + s1) + (s2 + s3);
    __syncthreads();
    if (t < 256) st[t] = (sh[t] + sh[t + 256]) + (sh[t + 512] + sh[t + 768]);
}

// ---------- final GEMM with BN+ReLU applied to A on read ----------
__global__ __launch_bounds__(256) void k_out(const uint16_t* __restrict__ A,
                                             const uint16_t* __restrict__ Wf,
                                             const float* __restrict__ bias,
                                             const float* __restrict__ st, float ninv,
                                             void* __restrict__ out, int N,
                                             const int* __restrict__ flags){
    __shared__ __align__(16) uint16_t wlds[6144];
    __shared__ float s_m[128], s_iv[128];
    int t = threadIdx.x;
    {
        const uint4* s = (const uint4*)Wf;
        uint4* d = (uint4*)wlds;
        for (int i = t; i < 768; i += 256) d[i] = s[i];
    }
    if (t < 128){
        float m = st[t] * ninv;
        float var = st[128 + t] * ninv - m * m;
        s_m[t] = m;
        s_iv[t] = rsqrtf(var + 1e-5f);
    }
    __syncthreads();
    int lane = t & 63, wave = t >> 6;
    int m = lane & 15, q = lane >> 4;
    int row_base = blockIdx.x * 64 + wave * 16;
    int arow = row_base + m;
    if (arow >= N) arow = N - 1;
    short8 afrag[4];
    const uint4* ap = (const uint4*)(A + (size_t)arow * 128);
    #pragma unroll
    for (int kt = 0; kt < 4; kt++){
        uint4 u = ap[kt * 4 + q];
        float v[8] = {blo(u.x), bhi(u.x), blo(u.y), bhi(u.y),
                      blo(u.z), bhi(u.z), blo(u.w), bhi(u.w)};
        int c0 = kt * 32 + q * 8;
        #pragma unroll
        for (int j = 0; j < 8; j++) v[j] = fmaxf((v[j] - s_m[c0 + j]) * s_iv[c0 + j], 0.f);
        uint4 o;
        o.x = pack2(v[0], v[1]); o.y = pack2(v[2], v[3]);
        o.z = pack2(v[4], v[5]); o.w = pack2(v[6], v[7]);
        afrag[kt] = *(short8*)&o;
    }
    floatx4 acc[3];
    #pragma unroll
    for (int nt = 0; nt < 3; nt++) acc[nt] = (floatx4){0.f, 0.f, 0.f, 0.f};
    const short8* wl = (const short8*)wlds;
    #pragma unroll
    for (int kt = 0; kt < 4; kt++){
        #pragma unroll
        for (int nt = 0; nt < 3; nt++){
            acc[nt] = __builtin_amdgcn_mfma_f32_16x16x32_bf16(afrag[kt], wl[(kt * 3 + nt) * 64 + lane], acc[nt], 0, 0, 0);
        }
    }
    int isbf = flags[1];
    #pragma unroll
    for (int nt = 0; nt < 3; nt++){
        int ccol = nt * 16 + m;
        if (ccol < 40){
            float bv = bias[ccol];
            #pragma unroll
            for (int r = 0; r < 4; r++){
                int grow = row_base + q * 4 + r;
                if (grow < N){
                    float y = acc[nt][r] + bv;
                    if (isbf) ((uint16_t*)out)[(size_t)grow * 40 + ccol] = f2b(y);
                    else      ((float*)out)[(size_t)grow * 40 + ccol] = y;
                }
            }
        }
    }
}

extern "C" void kernel_launch(void* const* d_in, const int* in_sizes, int n_in,
                              void* d_out, int out_size, void* d_ws, size_t ws_size,
                              hipStream_t stream){
    (void)n_in;
    const void* x  = d_in[0];
    const int* ei  = (const int*)d_in[1];
    const void* W0 = d_in[2];
    const void* b0 = d_in[3];
    const void* W1 = d_in[4];
    const void* b1 = d_in[5];
    const void* W2 = d_in[6];
    const void* b2 = d_in[7];
    const void* Wl = d_in[8];
    const void* bl = d_in[9];

    const int N = in_sizes[0] / 128;
    const int E = in_sizes[1] / 2;
    const int NF = N * 128;
    const int NB = (N + 255) / 256;
    const int gemm_blocks2 = (N + 127) / 128;   // 128-row blocks
    const int gemm_blocks  = (N + 63) / 64;     // k_out blocks

    // ---- workspace layout ----
    char* ws = (char*)d_ws;
    size_t off = 0;
    uint16_t* hx = (uint16_t*)(ws + off); off += ((size_t)NF * 2 + 255) & ~(size_t)255;
    uint16_t* ag = (uint16_t*)(ws + off); off += ((size_t)NF * 2 + 255) & ~(size_t)255;
    int* col     = (int*)(ws + off);      off += ((size_t)E * 4 + 255) & ~(size_t)255;
    int* rp      = (int*)(ws + off);      off += ((size_t)(N + 1) * 4 + 255) & ~(size_t)255;
    int* cur     = (int*)(ws + off);      off += ((size_t)N * 4 + 255) & ~(size_t)255;
    int* deg     = (int*)(ws + off);      off += ((size_t)N * 4 + 255) & ~(size_t)255;
    int* bsum    = (int*)(ws + off);      off += 512 * 4;
    int* flags   = (int*)(ws + off);      off += 256;
    uint16_t* Wf0 = (uint16_t*)(ws + off); off += 16384 * 2;
    uint16_t* Wf1 = (uint16_t*)(ws + off); off += 16384 * 2;
    uint16_t* Wf2 = (uint16_t*)(ws + off); off += 16384 * 2;
    uint16_t* Wfl = (uint16_t*)(ws + off); off += 6144 * 2;
    float* bc    = (float*)(ws + off);    off += 424 * 4 + 160;
    float* stats = (float*)(ws + off);    off += 768 * 4;   // 3 layers x (sum[128], ssq[128])
    float* part  = (float*)(ws + off);    off += (size_t)gemm_blocks2 * 256 * 4;
    const size_t required = off;

    if (ws_size < required){
        int nwords = out_size / 2;
        k_sentinel<<<(nwords + 255) / 256, 256, 0, stream>>>((uint32_t*)d_out, nwords, 0x40004000u);
        return;
    }

    // ---- flags, zeroing, CSR ----
    k_flags<<<1, 64, 0, stream>>>((const uint32_t*)x, ei, flags);
    k_zero<<<(N + 255) / 256, 256, 0, stream>>>(deg, N);
    k_deg<<<(E + 255) / 256, 256, 0, stream>>>(ei, E, deg, flags);
    k_scan1<<<NB, 256, 0, stream>>>(deg, N, bsum);
    k_scan2<<<1, 512, 0, stream>>>(bsum, NB, rp, N);
    k_scan3<<<NB, 256, 0, stream>>>(deg, N, bsum, rp, cur);
    k_fill<<<(E + 255) / 256, 256, 0, stream>>>(ei, E, cur, col, flags);

    // ---- conversions / weight prep ----
    k_cvt_x<<<2048, 256, 0, stream>>>(x, hx, NF, flags);
    k_prep_all<<<216, 256, 0, stream>>>(W0, W1, W2, Wl, Wf0, Wf1, Wf2, Wfl, flags);
    k_cvt_bias<<<2, 256, 0, stream>>>(b0, b1, b2, bl, bc, flags);

    const float ninv = 1.0f / (float)N;
    const int agg_blocks = (N + 15) / 16;
    const uint16_t* xr = (const uint16_t*)x;

    // layer 0: agg(x) -> ag, gemm in place (Y0 in ag), stats0
    k_agg<<<agg_blocks, 256, 0, stream>>>(hx, xr, rp, col, ag, N, stats, 0, ninv, flags);
    k_gemm<<<gemm_blocks2, 256, 0, stream>>>(ag, Wf0, bc, part, N);
    k_red<<<1, 1024, 0, stream>>>(part, gemm_blocks2, stats);
    // layer 1: agg(bn0(Y0)) -> hx, gemm in place (Y1 in hx), stats1
    k_agg<<<agg_blocks, 256, 0, stream>>>(ag, xr, rp, col, hx, N, stats, 1, ninv, flags);
    k_gemm<<<gemm_blocks2, 256, 0, stream>>>(hx, Wf1, bc + 128, part, N);
    k_red<<<1, 1024, 0, stream>>>(part, gemm_blocks2, stats + 256);
    // layer 2: agg(bn1(Y1)) -> ag, gemm in place (Y2 in ag), stats2
    k_agg<<<agg_blocks, 256, 0, stream>>>(hx, xr, rp, col, ag, N, stats + 256, 1, ninv, flags);
    k_gemm<<<gemm_blocks2, 256, 0, stream>>>(ag, Wf2, bc + 256, part, N);
    k_red<<<1, 1024, 0, stream>>>(part, gemm_blocks2, stats + 512);
    // final: out = bn2(Y2)relu @ Wl + bl
    k_out<<<gemm_blocks, 256, 0, stream>>>(ag, Wfl, bc + 384, stats + 512, ninv, d_out, N, flags);
}